// Round 1
// baseline (1698.541 us; speedup 1.0000x reference)
//
#include <hip/hip_runtime.h>
#include <hip/hip_bf16.h>
#include <cstdint>
#include <cstddef>

// SGM fused pipeline, MI355X gfx950.
// Shapes: B=32 L=64 N=1024 D=512 C=8192 WS=3 NH=16 HD=32 HID=1024
// Encoder rows M=12288 (side*6144 + pos*3 + w), cross rows 4096 (side*2048+pos).

typedef __attribute__((ext_vector_type(8))) short s16x8;
typedef __attribute__((ext_vector_type(8))) unsigned short u16x8;
typedef __attribute__((ext_vector_type(4))) unsigned short u16x4;
typedef __attribute__((ext_vector_type(4))) float f32x4;

__device__ __forceinline__ float b2f(unsigned short u) {
  union { unsigned int i; float f; } c; c.i = ((unsigned int)u) << 16; return c.f;
}
__device__ __forceinline__ unsigned short f2b(float f) {
  union { float f; unsigned int i; } c; c.f = f;
  unsigned int x = c.i;
  return (unsigned short)((x + 0x7FFFu + ((x >> 16) & 1u)) >> 16); // RNE, no NaN in this net
}

// ---------------- fp32 -> bf16 convert (weights) ----------------
__global__ void cvt_f32_bf16(const float* __restrict__ s, unsigned short* __restrict__ d, int n4) {
  int i = blockIdx.x * 256 + threadIdx.x;
  if (i >= n4) return;
  float4 v = ((const float4*)s)[i];
  u16x4 o; o[0] = f2b(v.x); o[1] = f2b(v.y); o[2] = f2b(v.z); o[3] = f2b(v.w);
  *(u16x4*)(d + (size_t)i * 4) = o;
}

// ---------------- embedding + token add ----------------
// x[row][d] = char_embed[id(row)][d] + tok(side)[d], row = side*6144 + pos*3 + w
__global__ void embed_k(const int* __restrict__ targets, const int* __restrict__ pad_p,
                        const float* __restrict__ ce, const float* __restrict__ ltok,
                        const float* __restrict__ rtok, float* __restrict__ x) {
  int idx = blockIdx.x * 256 + threadIdx.x;   // float4 index, 12288*128 total
  if (idx >= 12288 * 128) return;
  int row = idx >> 7, d4 = idx & 127;
  int side = row >= 6144;
  int rem = row - side * 6144;
  int pos = rem / 3, w = rem - pos * 3;
  int b = pos >> 6, l = pos & 63;
  int id;
  if (!side) { int ti = l + w - 3; id = (ti >= 0) ? targets[(b << 6) + ti] : *pad_p; }
  else       { int ti = l + w + 1; id = (ti < 64) ? targets[(b << 6) + ti] : *pad_p; }
  float4 cv = ((const float4*)ce)[(size_t)id * 128 + d4];
  float4 tv = ((const float4*)(side ? rtok : ltok))[d4];
  float4 o; o.x = cv.x + tv.x; o.y = cv.y + tv.y; o.z = cv.z + tv.z; o.w = cv.w + tv.w;
  ((float4*)x)[idx] = o;
}

// ---------------- LayerNorm (D=512, fp32 in -> bf16 out), one wave per row ----------------
__global__ __launch_bounds__(256) void ln_rows(const float* __restrict__ in,
    const float* __restrict__ g, const float* __restrict__ b,
    unsigned short* __restrict__ out, int M) {
  int row = blockIdx.x * 4 + (threadIdx.x >> 6);
  int lane = threadIdx.x & 63;
  const float* rp = in + (size_t)row * 512;
  float4 v0 = ((const float4*)rp)[lane * 2];
  float4 v1 = ((const float4*)rp)[lane * 2 + 1];
  float vv[8] = {v0.x, v0.y, v0.z, v0.w, v1.x, v1.y, v1.z, v1.w};
  float s = 0.f, ss = 0.f;
#pragma unroll
  for (int j = 0; j < 8; ++j) { s += vv[j]; ss += vv[j] * vv[j]; }
#pragma unroll
  for (int o = 1; o < 64; o <<= 1) { s += __shfl_xor(s, o); ss += __shfl_xor(ss, o); }
  float mean = s * (1.0f / 512.0f);
  float var = ss * (1.0f / 512.0f) - mean * mean;
  float inv = rsqrtf(var + 1e-5f);
  int c = lane * 8;
  u16x8 o8;
#pragma unroll
  for (int j = 0; j < 8; ++j) o8[j] = f2b((vv[j] - mean) * inv * g[c + j] + b[c + j]);
  *(u16x8*)(out + (size_t)row * 512 + c) = o8;
}

// ---------------- bf16 MFMA GEMM: C[M,N] = A[M,K] @ Bt[N,K]^T + bias (+res) (gelu?) ----------------
// 128x128 tile, BK=32, 4 waves each own 64x64. LDS stride 40 (pad) -> <=2-way bank alias (free).
template<int RES, int GELU, int OUTBF>
__global__ __launch_bounds__(256) void gemm_bt(
    const unsigned short* __restrict__ A, const unsigned short* __restrict__ Bt,
    const float* __restrict__ bias, const float* __restrict__ res,
    void* __restrict__ outp, int M, int N, int K) {
  __shared__ unsigned short sA[128 * 40];
  __shared__ unsigned short sB[128 * 40];
  const int tid = threadIdx.x;
  const int bm = blockIdx.y * 128, bn = blockIdx.x * 128;
  const int wave = tid >> 6, lane = tid & 63;
  const int wr = (wave >> 1) * 64, wc = (wave & 1) * 64;
  const int lrow = lane & 15, lk = (lane >> 4) * 8;
  f32x4 acc[4][4] = {};
  const int sr = tid >> 1;
  const int sc = (tid & 1) * 16;
  const unsigned short* ga = A + (size_t)(bm + sr) * K + sc;
  const unsigned short* gb = Bt + (size_t)(bn + sr) * K + sc;
  for (int k0 = 0; k0 < K; k0 += 32) {
    __syncthreads();
    *(u16x8*)&sA[sr * 40 + sc]     = *(const u16x8*)(ga + k0);
    *(u16x8*)&sA[sr * 40 + sc + 8] = *(const u16x8*)(ga + k0 + 8);
    *(u16x8*)&sB[sr * 40 + sc]     = *(const u16x8*)(gb + k0);
    *(u16x8*)&sB[sr * 40 + sc + 8] = *(const u16x8*)(gb + k0 + 8);
    __syncthreads();
    s16x8 av[4], bv[4];
#pragma unroll
    for (int m = 0; m < 4; ++m) av[m] = *(const s16x8*)&sA[(wr + m * 16 + lrow) * 40 + lk];
#pragma unroll
    for (int n = 0; n < 4; ++n) bv[n] = *(const s16x8*)&sB[(wc + n * 16 + lrow) * 40 + lk];
#pragma unroll
    for (int m = 0; m < 4; ++m)
#pragma unroll
      for (int n = 0; n < 4; ++n)
        acc[m][n] = __builtin_amdgcn_mfma_f32_16x16x32_bf16(av[m], bv[n], acc[m][n], 0, 0, 0);
  }
  const int orow0 = bm + wr + (lane >> 4) * 4;
  const int ocol0 = bn + wc + (lane & 15);
#pragma unroll
  for (int m = 0; m < 4; ++m) {
#pragma unroll
    for (int n = 0; n < 4; ++n) {
#pragma unroll
      for (int r = 0; r < 4; ++r) {
        int row = orow0 + m * 16 + r;
        int col = ocol0 + n * 16;
        float v = acc[m][n][r] + bias[col];
        if (GELU) v = 0.5f * v * (1.0f + erff(v * 0.70710678118654752f));
        if (RES) v += res[(size_t)row * N + col];
        if (OUTBF) ((unsigned short*)outp)[(size_t)row * N + col] = f2b(v);
        else       ((float*)outp)[(size_t)row * N + col] = v;
      }
    }
  }
}

// ---------------- windowed (WS=3) attention, thread per (side-pos, head, q-row) ----------------
__global__ __launch_bounds__(256) void winattn(const unsigned short* __restrict__ qkv,
                                               unsigned short* __restrict__ o) {
  int g = blockIdx.x * 256 + threadIdx.x;
  if (g >= 4096 * 48) return;
  int i = g % 3;
  int t = g / 3;
  int h = t & 15;
  int sp = t >> 4;
  const unsigned short* base = qkv + (size_t)sp * 4608 + h * 32;
  float qv[32];
  {
    const u16x8* qp = (const u16x8*)(base + (size_t)i * 1536);
#pragma unroll
    for (int c = 0; c < 4; ++c) {
      u16x8 v = qp[c];
#pragma unroll
      for (int j = 0; j < 8; ++j) qv[c * 8 + j] = b2f(v[j]);
    }
  }
  float s[3];
#pragma unroll
  for (int j3 = 0; j3 < 3; ++j3) {
    const u16x8* kp = (const u16x8*)(base + (size_t)j3 * 1536 + 512);
    float acc = 0.f;
#pragma unroll
    for (int c = 0; c < 4; ++c) {
      u16x8 v = kp[c];
#pragma unroll
      for (int j = 0; j < 8; ++j) acc += qv[c * 8 + j] * b2f(v[j]);
    }
    s[j3] = acc * 0.17677669529663687f;
  }
  float mx = fmaxf(s[0], fmaxf(s[1], s[2]));
  float e0 = __expf(s[0] - mx), e1 = __expf(s[1] - mx), e2 = __expf(s[2] - mx);
  float inv = 1.0f / (e0 + e1 + e2);
  float a0 = e0 * inv, a1 = e1 * inv, a2 = e2 * inv;
  unsigned short* op = o + (size_t)(sp * 3 + i) * 512 + h * 32;
  const u16x8* v0p = (const u16x8*)(base + 1024);
  const u16x8* v1p = (const u16x8*)(base + 1536 + 1024);
  const u16x8* v2p = (const u16x8*)(base + 3072 + 1024);
#pragma unroll
  for (int c = 0; c < 4; ++c) {
    u16x8 x0 = v0p[c], x1 = v1p[c], x2 = v2p[c];
    u16x8 ov;
#pragma unroll
    for (int j = 0; j < 8; ++j)
      ov[j] = f2b(a0 * b2f(x0[j]) + a1 * b2f(x1[j]) + a2 * b2f(x2[j]));
    *(u16x8*)(op + c * 8) = ov;
  }
}

// ---------------- mean over WS=3 ----------------
__global__ void mean3(const float* __restrict__ x, float* __restrict__ enc) {
  int i = blockIdx.x * 256 + threadIdx.x;   // float4 index, 4096*128
  if (i >= 4096 * 128) return;
  int p = i >> 7, d4 = i & 127;
  const float4* xp = (const float4*)x;
  float4 a = xp[(size_t)(p * 3 + 0) * 128 + d4];
  float4 b = xp[(size_t)(p * 3 + 1) * 128 + d4];
  float4 c = xp[(size_t)(p * 3 + 2) * 128 + d4];
  float4 o;
  o.x = (a.x + b.x + c.x) * (1.0f / 3.0f);
  o.y = (a.y + b.y + c.y) * (1.0f / 3.0f);
  o.z = (a.z + b.z + c.z) * (1.0f / 3.0f);
  o.w = (a.w + b.w + c.w) * (1.0f / 3.0f);
  ((float4*)enc)[i] = o;
}

// ---------------- cross attention: block per (side,b,h); 4 threads per q-row ----------------
__global__ __launch_bounds__(256) void crossattn(const float* __restrict__ q,
    const unsigned short* __restrict__ kv, unsigned short* __restrict__ o) {
  __shared__ float qs[64 * 32];
  int sbh = blockIdx.x;
  int side = sbh >> 9, b = (sbh >> 4) & 31, h = sbh & 15;
  int tid = threadIdx.x;
  {
    int l0 = tid >> 2, d0 = (tid & 3) * 8;
    const float* qp = q + (size_t)(side * 2048 + b * 64 + l0) * 512 + h * 32 + d0;
    float4 a = ((const float4*)qp)[0];
    float4 c = ((const float4*)qp)[1];
    *(float4*)&qs[l0 * 32 + d0] = a;
    *(float4*)&qs[l0 * 32 + d0 + 4] = c;
  }
  __syncthreads();
  const int l = tid >> 2, t4 = tid & 3;
  const float* ql = &qs[l * 32];
  const unsigned short* kbase = kv + (size_t)b * 1024 * 1024 + h * 32;
  const float SC = 0.17677669529663687f;
  float mt = -1e30f;
  for (int n = t4; n < 1024; n += 4) {           // pass 1: max of scores
    const u16x8* kp = (const u16x8*)(kbase + (size_t)n * 1024);
    float acc = 0.f;
#pragma unroll
    for (int c = 0; c < 4; ++c) {
      u16x8 v = kp[c];
#pragma unroll
      for (int j = 0; j < 8; ++j) acc += ql[c * 8 + j] * b2f(v[j]);
    }
    mt = fmaxf(mt, acc * SC);
  }
  float se = 0.f;
  float oa[32];
#pragma unroll
  for (int d = 0; d < 32; ++d) oa[d] = 0.f;
  for (int n = t4; n < 1024; n += 4) {           // pass 2: exp-weighted accumulate
    const unsigned short* krow = kbase + (size_t)n * 1024;
    const u16x8* kp = (const u16x8*)krow;
    float acc = 0.f;
#pragma unroll
    for (int c = 0; c < 4; ++c) {
      u16x8 v = kp[c];
#pragma unroll
      for (int j = 0; j < 8; ++j) acc += ql[c * 8 + j] * b2f(v[j]);
    }
    float e = __expf(acc * SC - mt);
    se += e;
    const u16x8* vp = (const u16x8*)(krow + 512);
#pragma unroll
    for (int c = 0; c < 4; ++c) {
      u16x8 v = vp[c];
#pragma unroll
      for (int j = 0; j < 8; ++j) oa[c * 8 + j] += e * b2f(v[j]);
    }
  }
  // combine the 4 threads of this q-row (contiguous lanes)
  float M4 = fmaxf(mt, __shfl_xor(mt, 1)); M4 = fmaxf(M4, __shfl_xor(M4, 2));
  float f = __expf(mt - M4);
  float ses = se * f; ses += __shfl_xor(ses, 1); ses += __shfl_xor(ses, 2);
  float rinv = 1.0f / ses;
  unsigned short* op = o + (size_t)(side * 2048 + b * 64 + l) * 512 + h * 32;
#pragma unroll
  for (int c = 0; c < 4; ++c) {
    float r[8];
#pragma unroll
    for (int j = 0; j < 8; ++j) {
      float v = oa[c * 8 + j] * f;
      v += __shfl_xor(v, 1); v += __shfl_xor(v, 2);
      r[j] = v * rinv;
    }
    if (c == t4) {
      u16x8 ov;
#pragma unroll
      for (int j = 0; j < 8; ++j) ov[j] = f2b(r[j]);
      *(u16x8*)(op + c * 8) = ov;
    }
  }
}

// ---------------- targets pass-through (output 2) ----------------
__global__ void tail_targets(const int* __restrict__ t, float* __restrict__ out) {
  int i = blockIdx.x * 256 + threadIdx.x;
  if (i < 2048) out[33554432 + i] = (float)t[i];
}

extern "C" void kernel_launch(void* const* d_in, const int* in_sizes, int n_in,
                              void* d_out, int out_size, void* d_ws, size_t ws_size,
                              hipStream_t stream) {
  const float* visual   = (const float*)d_in[0];
  const int*   targets  = (const int*)d_in[1];
  const int*   pad_p    = (const int*)d_in[2];
  const float* char_emb = (const float*)d_in[3];
  const float* ln1_g = (const float*)d_in[4];
  const float* ln1_b = (const float*)d_in[5];
  const float* in_proj_w = (const float*)d_in[6];
  const float* in_proj_b = (const float*)d_in[7];
  const float* out_w = (const float*)d_in[8];
  const float* out_b = (const float*)d_in[9];
  const float* fc1_w = (const float*)d_in[10];
  const float* fc1_b = (const float*)d_in[11];
  const float* fc2_w = (const float*)d_in[12];
  const float* fc2_b = (const float*)d_in[13];
  const float* ln2_g = (const float*)d_in[14];
  const float* ln2_b = (const float*)d_in[15];
  const float* ltok  = (const float*)d_in[16];
  const float* rtok  = (const float*)d_in[17];
  const float* q_w   = (const float*)d_in[18];
  const float* q_b   = (const float*)d_in[19];
  const float* kv_w  = (const float*)d_in[20];
  const float* kv_b  = (const float*)d_in[21];
  const float* proj_w = (const float*)d_in[22];
  const float* proj_b = (const float*)d_in[23];
  const float* lnq_g = (const float*)d_in[24];
  const float* lnq_b = (const float*)d_in[25];
  const float* lnkv_g = (const float*)d_in[26];
  const float* lnkv_b = (const float*)d_in[27];
  const float* head_w = (const float*)d_in[28];
  const float* head_b = (const float*)d_in[29];

  // workspace layout (bytes); KV (bf16, 67MB) aliases the dead encoder region
  char* ws = (char*)d_ws;
  unsigned short* W    = (unsigned short*)ws;                    // 14,680,064 B weights bf16
  float*          X    = (float*)(ws + 14680064ull);             // 25,165,824 B x fp32 12288x512
  unsigned short* KV   = (unsigned short*)(ws + 14680064ull);    // alias: 67,108,864 B kv bf16 32768x1024
  unsigned short* A1   = (unsigned short*)(ws + 39845888ull);    // 12,582,912 B bf16 12288x512
  unsigned short* B1   = (unsigned short*)(ws + 52428800ull);    // 25,165,824 B bf16 12288x1024
  unsigned short* QKV  = (unsigned short*)(ws + 77594624ull);    // 37,748,736 B bf16 12288x1536
  float*          ENC  = (float*)(ws + 115343360ull);            //  8,388,608 B fp32 4096x512
  unsigned short* VIS  = (unsigned short*)(ws + 123731968ull);   // 33,554,432 B bf16 32768x512
  float*          Q    = (float*)(ws + 157286400ull);            //  8,388,608 B fp32 4096x512
  unsigned short* OC   = (unsigned short*)(ws + 165675008ull);   //  4,194,304 B bf16 4096x512
  unsigned short* FEAT = (unsigned short*)(ws + 169869312ull);   //  4,194,304 B bf16 4096x512
  unsigned short* LNQ  = (unsigned short*)(ws + 174063616ull);   //  4,194,304 B bf16 4096x512
  // total required: 178,257,920 B

  unsigned short* Wip   = W;
  unsigned short* Wout  = W + 786432;
  unsigned short* Wfc1  = W + 1048576;
  unsigned short* Wfc2  = W + 1572864;
  unsigned short* Wq    = W + 2097152;
  unsigned short* Wkv   = W + 2359296;
  unsigned short* Wproj = W + 2883584;
  unsigned short* Whead = W + 3145728;

  auto cvt = [&](const float* s, unsigned short* d, int n) {
    cvt_f32_bf16<<<dim3((n / 4 + 255) / 256), dim3(256), 0, stream>>>(s, d, n / 4);
  };
  cvt(in_proj_w, Wip, 786432);
  cvt(out_w, Wout, 262144);
  cvt(fc1_w, Wfc1, 524288);
  cvt(fc2_w, Wfc2, 524288);
  cvt(q_w, Wq, 262144);
  cvt(kv_w, Wkv, 524288);
  cvt(proj_w, Wproj, 262144);
  cvt(head_w, Whead, 4194304);

  // ---- encoders (left+right batched, M=12288) ----
  embed_k<<<dim3(6144), dim3(256), 0, stream>>>(targets, pad_p, char_emb, ltok, rtok, X);
  ln_rows<<<dim3(3072), dim3(256), 0, stream>>>(X, ln1_g, ln1_b, A1, 12288);
  gemm_bt<0,0,1><<<dim3(12, 96), dim3(256), 0, stream>>>(A1, Wip, in_proj_b, nullptr, QKV, 12288, 1536, 512);
  winattn<<<dim3(768), dim3(256), 0, stream>>>(QKV, B1);
  gemm_bt<1,0,0><<<dim3(4, 96), dim3(256), 0, stream>>>(B1, Wout, out_b, X, X, 12288, 512, 512);
  ln_rows<<<dim3(3072), dim3(256), 0, stream>>>(X, ln2_g, ln2_b, A1, 12288);
  gemm_bt<0,1,1><<<dim3(8, 96), dim3(256), 0, stream>>>(A1, Wfc1, fc1_b, nullptr, B1, 12288, 1024, 512);
  gemm_bt<1,0,0><<<dim3(4, 96), dim3(256), 0, stream>>>(B1, Wfc2, fc2_b, X, X, 12288, 512, 1024);
  mean3<<<dim3(2048), dim3(256), 0, stream>>>(X, ENC);

  // ---- cross attention (kv shared by both sides; encoder buffers now dead) ----
  ln_rows<<<dim3(8192), dim3(256), 0, stream>>>(visual, lnkv_g, lnkv_b, VIS, 32768);
  gemm_bt<0,0,1><<<dim3(8, 256), dim3(256), 0, stream>>>(VIS, Wkv, kv_b, nullptr, KV, 32768, 1024, 512);
  ln_rows<<<dim3(1024), dim3(256), 0, stream>>>(ENC, lnq_g, lnq_b, LNQ, 4096);
  gemm_bt<0,0,0><<<dim3(4, 32), dim3(256), 0, stream>>>(LNQ, Wq, q_b, nullptr, Q, 4096, 512, 512);
  crossattn<<<dim3(1024), dim3(256), 0, stream>>>(Q, KV, OC);
  gemm_bt<1,0,1><<<dim3(4, 32), dim3(256), 0, stream>>>(OC, Wproj, proj_b, ENC, FEAT, 4096, 512, 512);

  // ---- head -> d_out (rows 0..2047 = sgm_left, 2048..4095 = sgm_right) ----
  gemm_bt<0,0,0><<<dim3(64, 32), dim3(256), 0, stream>>>(FEAT, Whead, head_b, nullptr, (float*)d_out, 4096, 8192, 512);
  tail_targets<<<dim3(8), dim3(256), 0, stream>>>(targets, (float*)d_out);
}

// Round 2
// 476.903 us; speedup vs baseline: 3.5616x; 3.5616x over previous
//
#include <hip/hip_runtime.h>
#include <hip/hip_bf16.h>
#include <cstdint>
#include <cstddef>

// SGM fused pipeline, MI355X gfx950.
// Shapes: B=32 L=64 N=1024 D=512 C=8192 WS=3 NH=16 HD=32 HID=1024
// Encoder rows M=12288 (side*6144 + pos*3 + w), cross rows 4096 (side*2048+pos).

typedef __attribute__((ext_vector_type(8))) short s16x8;
typedef __attribute__((ext_vector_type(8))) unsigned short u16x8;
typedef __attribute__((ext_vector_type(4))) unsigned short u16x4;
typedef __attribute__((ext_vector_type(4))) float f32x4;

__device__ __forceinline__ float b2f(unsigned short u) {
  union { unsigned int i; float f; } c; c.i = ((unsigned int)u) << 16; return c.f;
}
__device__ __forceinline__ unsigned short f2b(float f) {
  union { float f; unsigned int i; } c; c.f = f;
  unsigned int x = c.i;
  return (unsigned short)((x + 0x7FFFu + ((x >> 16) & 1u)) >> 16); // RNE, no NaN in this net
}

// ---------------- fp32 -> bf16 convert (weights) ----------------
__global__ void cvt_f32_bf16(const float* __restrict__ s, unsigned short* __restrict__ d, int n4) {
  int i = blockIdx.x * 256 + threadIdx.x;
  if (i >= n4) return;
  float4 v = ((const float4*)s)[i];
  u16x4 o; o[0] = f2b(v.x); o[1] = f2b(v.y); o[2] = f2b(v.z); o[3] = f2b(v.w);
  *(u16x4*)(d + (size_t)i * 4) = o;
}

// ---------------- embedding + token add ----------------
__global__ void embed_k(const int* __restrict__ targets, const int* __restrict__ pad_p,
                        const float* __restrict__ ce, const float* __restrict__ ltok,
                        const float* __restrict__ rtok, float* __restrict__ x) {
  int idx = blockIdx.x * 256 + threadIdx.x;   // float4 index, 12288*128 total
  if (idx >= 12288 * 128) return;
  int row = idx >> 7, d4 = idx & 127;
  int side = row >= 6144;
  int rem = row - side * 6144;
  int pos = rem / 3, w = rem - pos * 3;
  int b = pos >> 6, l = pos & 63;
  int id;
  if (!side) { int ti = l + w - 3; id = (ti >= 0) ? targets[(b << 6) + ti] : *pad_p; }
  else       { int ti = l + w + 1; id = (ti < 64) ? targets[(b << 6) + ti] : *pad_p; }
  float4 cv = ((const float4*)ce)[(size_t)id * 128 + d4];
  float4 tv = ((const float4*)(side ? rtok : ltok))[d4];
  float4 o; o.x = cv.x + tv.x; o.y = cv.y + tv.y; o.z = cv.z + tv.z; o.w = cv.w + tv.w;
  ((float4*)x)[idx] = o;
}

// ---------------- LayerNorm (D=512, fp32 in -> bf16 out), one wave per row ----------------
__global__ __launch_bounds__(256) void ln_rows(const float* __restrict__ in,
    const float* __restrict__ g, const float* __restrict__ b,
    unsigned short* __restrict__ out, int M) {
  int row = blockIdx.x * 4 + (threadIdx.x >> 6);
  int lane = threadIdx.x & 63;
  const float* rp = in + (size_t)row * 512;
  float4 v0 = ((const float4*)rp)[lane * 2];
  float4 v1 = ((const float4*)rp)[lane * 2 + 1];
  float vv[8] = {v0.x, v0.y, v0.z, v0.w, v1.x, v1.y, v1.z, v1.w};
  float s = 0.f, ss = 0.f;
#pragma unroll
  for (int j = 0; j < 8; ++j) { s += vv[j]; ss += vv[j] * vv[j]; }
#pragma unroll
  for (int o = 1; o < 64; o <<= 1) { s += __shfl_xor(s, o); ss += __shfl_xor(ss, o); }
  float mean = s * (1.0f / 512.0f);
  float var = ss * (1.0f / 512.0f) - mean * mean;
  float inv = rsqrtf(var + 1e-5f);
  int c = lane * 8;
  u16x8 o8;
#pragma unroll
  for (int j = 0; j < 8; ++j) o8[j] = f2b((vv[j] - mean) * inv * g[c + j] + b[c + j]);
  *(u16x8*)(out + (size_t)row * 512 + c) = o8;
}

// ---------------- bf16 MFMA GEMM: C[M,N] = A[M,K] @ Bt[N,K]^T + bias (+res) (gelu?) ----------------
// 128x128 tile, BK=32, 4 waves each own 64x64. LDS stride 40 (pad) -> <=2-way bank alias.
// KVT=1: N=1024 KV projection; writes K to Kp[b][h][n][32] and V^T to VpT[b][h][d][n].
template<int RES, int GELU, int OUTBF, int KVT>
__global__ __launch_bounds__(256) void gemm_bt(
    const unsigned short* __restrict__ A, const unsigned short* __restrict__ Bt,
    const float* __restrict__ bias, const float* __restrict__ res,
    void* __restrict__ outp, int M, int N, int K) {
  __shared__ unsigned short sA[128 * 40];
  __shared__ unsigned short sB[128 * 40];
  const int tid = threadIdx.x;
  const int bm = blockIdx.y * 128, bn = blockIdx.x * 128;
  const int wave = tid >> 6, lane = tid & 63;
  const int wr = (wave >> 1) * 64, wc = (wave & 1) * 64;
  const int lrow = lane & 15, lk = (lane >> 4) * 8;
  f32x4 acc[4][4] = {};
  const int sr = tid >> 1;
  const int sc = (tid & 1) * 16;
  const unsigned short* ga = A + (size_t)(bm + sr) * K + sc;
  const unsigned short* gb = Bt + (size_t)(bn + sr) * K + sc;
  for (int k0 = 0; k0 < K; k0 += 32) {
    __syncthreads();
    *(u16x8*)&sA[sr * 40 + sc]     = *(const u16x8*)(ga + k0);
    *(u16x8*)&sA[sr * 40 + sc + 8] = *(const u16x8*)(ga + k0 + 8);
    *(u16x8*)&sB[sr * 40 + sc]     = *(const u16x8*)(gb + k0);
    *(u16x8*)&sB[sr * 40 + sc + 8] = *(const u16x8*)(gb + k0 + 8);
    __syncthreads();
    s16x8 av[4], bv[4];
#pragma unroll
    for (int m = 0; m < 4; ++m) av[m] = *(const s16x8*)&sA[(wr + m * 16 + lrow) * 40 + lk];
#pragma unroll
    for (int n = 0; n < 4; ++n) bv[n] = *(const s16x8*)&sB[(wc + n * 16 + lrow) * 40 + lk];
#pragma unroll
    for (int m = 0; m < 4; ++m)
#pragma unroll
      for (int n = 0; n < 4; ++n)
        acc[m][n] = __builtin_amdgcn_mfma_f32_16x16x32_bf16(av[m], bv[n], acc[m][n], 0, 0, 0);
  }
  const int orow0 = bm + wr + (lane >> 4) * 4;
  const int ocol0 = bn + wc + (lane & 15);
#pragma unroll
  for (int m = 0; m < 4; ++m) {
#pragma unroll
    for (int n = 0; n < 4; ++n) {
#pragma unroll
      for (int r = 0; r < 4; ++r) {
        int row = orow0 + m * 16 + r;
        int col = ocol0 + n * 16;
        float v = acc[m][n][r] + bias[col];
        if (KVT) {
          // row = b*1024 + n_vis ; col<512 -> K head block, col>=512 -> V^T
          int bb = row >> 10, nn = row & 1023;
          unsigned short* Kp = (unsigned short*)outp;
          unsigned short* VpT = Kp + 16777216u;
          if (col < 512) {
            int hh = col >> 5, dd = col & 31;
            Kp[(((size_t)(bb * 16 + hh)) * 1024 + nn) * 32 + dd] = f2b(v);
          } else {
            int cc = col - 512, hh = cc >> 5, dd = cc & 31;
            VpT[(((size_t)(bb * 16 + hh)) * 32 + dd) * 1024 + nn] = f2b(v);
          }
        } else {
          if (GELU) v = 0.5f * v * (1.0f + erff(v * 0.70710678118654752f));
          if (RES) v += res[(size_t)row * N + col];
          if (OUTBF) ((unsigned short*)outp)[(size_t)row * N + col] = f2b(v);
          else       ((float*)outp)[(size_t)row * N + col] = v;
        }
      }
    }
  }
}

// ---------------- windowed (WS=3) attention, thread per (side-pos, head, q-row) ----------------
__global__ __launch_bounds__(256) void winattn(const unsigned short* __restrict__ qkv,
                                               unsigned short* __restrict__ o) {
  int g = blockIdx.x * 256 + threadIdx.x;
  if (g >= 4096 * 48) return;
  int i = g % 3;
  int t = g / 3;
  int h = t & 15;
  int sp = t >> 4;
  const unsigned short* base = qkv + (size_t)sp * 4608 + h * 32;
  float qv[32];
  {
    const u16x8* qp = (const u16x8*)(base + (size_t)i * 1536);
#pragma unroll
    for (int c = 0; c < 4; ++c) {
      u16x8 v = qp[c];
#pragma unroll
      for (int j = 0; j < 8; ++j) qv[c * 8 + j] = b2f(v[j]);
    }
  }
  float s[3];
#pragma unroll
  for (int j3 = 0; j3 < 3; ++j3) {
    const u16x8* kp = (const u16x8*)(base + (size_t)j3 * 1536 + 512);
    float acc = 0.f;
#pragma unroll
    for (int c = 0; c < 4; ++c) {
      u16x8 v = kp[c];
#pragma unroll
      for (int j = 0; j < 8; ++j) acc += qv[c * 8 + j] * b2f(v[j]);
    }
    s[j3] = acc * 0.17677669529663687f;
  }
  float mx = fmaxf(s[0], fmaxf(s[1], s[2]));
  float e0 = __expf(s[0] - mx), e1 = __expf(s[1] - mx), e2 = __expf(s[2] - mx);
  float inv = 1.0f / (e0 + e1 + e2);
  float a0 = e0 * inv, a1 = e1 * inv, a2 = e2 * inv;
  unsigned short* op = o + (size_t)(sp * 3 + i) * 512 + h * 32;
  const u16x8* v0p = (const u16x8*)(base + 1024);
  const u16x8* v1p = (const u16x8*)(base + 1536 + 1024);
  const u16x8* v2p = (const u16x8*)(base + 3072 + 1024);
#pragma unroll
  for (int c = 0; c < 4; ++c) {
    u16x8 x0 = v0p[c], x1 = v1p[c], x2 = v2p[c];
    u16x8 ov;
#pragma unroll
    for (int j = 0; j < 8; ++j)
      ov[j] = f2b(a0 * b2f(x0[j]) + a1 * b2f(x1[j]) + a2 * b2f(x2[j]));
    *(u16x8*)(op + c * 8) = ov;
  }
}

// ---------------- mean over WS=3 ----------------
__global__ void mean3(const float* __restrict__ x, float* __restrict__ enc) {
  int i = blockIdx.x * 256 + threadIdx.x;   // float4 index, 4096*128
  if (i >= 4096 * 128) return;
  int p = i >> 7, d4 = i & 127;
  const float4* xp = (const float4*)x;
  float4 a = xp[(size_t)(p * 3 + 0) * 128 + d4];
  float4 b = xp[(size_t)(p * 3 + 1) * 128 + d4];
  float4 c = xp[(size_t)(p * 3 + 2) * 128 + d4];
  float4 o;
  o.x = (a.x + b.x + c.x) * (1.0f / 3.0f);
  o.y = (a.y + b.y + c.y) * (1.0f / 3.0f);
  o.z = (a.z + b.z + c.z) * (1.0f / 3.0f);
  o.w = (a.w + b.w + c.w) * (1.0f / 3.0f);
  ((float4*)enc)[i] = o;
}

// ---------------- cross attention, MFMA flash style ----------------
// Block per (side,b,h): Q tile 64x32 (4 waves x 16 q-rows), KV 1024x32 streamed.
// Swapped orientation: S^T = mfma(K,Q) -> lane holds q = lane&15 (fixed), kv in regs.
// P repacked to B-fragment layout via per-wave LDS transpose (double-buffered).
// O^T += mfma(V^T, P): accumulator q = lane&15 matches softmax state.
__global__ __launch_bounds__(256) void crossattn_mfma(const float* __restrict__ q,
    const unsigned short* __restrict__ Kp, const unsigned short* __restrict__ VpT,
    unsigned short* __restrict__ o) {
  __shared__ unsigned short Plds[4][2][16 * 40];
  const int sbh = blockIdx.x;
  const int side = sbh >> 9, b = (sbh >> 4) & 31, h = sbh & 15;
  const int tid = threadIdx.x;
  const int w = tid >> 6, lane = tid & 63;
  const int ql = lane & 15, g = lane >> 4;
  const int qrow = side * 2048 + b * 64 + w * 16 + ql;
  const float SC = 0.17677669529663687f;
  // Q fragment (B-frag: lane holds Q[q=lane&15][d=g*8..g*8+7], pre-scaled)
  s16x8 qf;
  {
    const float* qp = q + (size_t)qrow * 512 + h * 32 + g * 8;
    float4 qa = ((const float4*)qp)[0];
    float4 qb4 = ((const float4*)qp)[1];
    qf[0] = (short)f2b(qa.x * SC); qf[1] = (short)f2b(qa.y * SC);
    qf[2] = (short)f2b(qa.z * SC); qf[3] = (short)f2b(qa.w * SC);
    qf[4] = (short)f2b(qb4.x * SC); qf[5] = (short)f2b(qb4.y * SC);
    qf[6] = (short)f2b(qb4.z * SC); qf[7] = (short)f2b(qb4.w * SC);
  }
  const unsigned short* kbase = Kp + ((size_t)(b * 16 + h) * 1024) * 32;
  const unsigned short* vbase = VpT + ((size_t)(b * 16 + h) * 32) * 1024;
  f32x4 oacc0 = {}, oacc1 = {};
  float m_run = -1e30f, l_part = 0.f;
  for (int kv0 = 0; kv0 < 1024; kv0 += 32) {
    const int pp = (kv0 >> 5) & 1;
    // K fragments: A-frag rows = kv
    s16x8 kf0 = *(const s16x8*)(kbase + (size_t)(kv0 + ql) * 32 + g * 8);
    s16x8 kf1 = *(const s16x8*)(kbase + (size_t)(kv0 + 16 + ql) * 32 + g * 8);
    f32x4 z = {0.f, 0.f, 0.f, 0.f};
    f32x4 s0 = __builtin_amdgcn_mfma_f32_16x16x32_bf16(kf0, qf, z, 0, 0, 0);
    f32x4 s1 = __builtin_amdgcn_mfma_f32_16x16x32_bf16(kf1, qf, z, 0, 0, 0);
    // online softmax; per lane: q = lane&15, kv = kv0 + 16t + g*4 + r
    float cm = fmaxf(fmaxf(fmaxf(s0[0], s0[1]), fmaxf(s0[2], s0[3])),
                     fmaxf(fmaxf(s1[0], s1[1]), fmaxf(s1[2], s1[3])));
    cm = fmaxf(cm, __shfl_xor(cm, 16));
    cm = fmaxf(cm, __shfl_xor(cm, 32));
    float m_new = fmaxf(m_run, cm);
    float corr = __expf(m_run - m_new);
    m_run = m_new;
    float p0[4], p1[4], ps = 0.f;
#pragma unroll
    for (int r = 0; r < 4; ++r) {
      p0[r] = __expf(s0[r] - m_new);
      p1[r] = __expf(s1[r] - m_new);
      ps += p0[r] + p1[r];
    }
    l_part = l_part * corr + ps;
    oacc0 *= corr; oacc1 *= corr;
    // P -> LDS (row q, cols kv_local), 4 consecutive kv per pack
    u16x4 w0, w1;
#pragma unroll
    for (int r = 0; r < 4; ++r) { w0[r] = f2b(p0[r]); w1[r] = f2b(p1[r]); }
    *(u16x4*)&Plds[w][pp][ql * 40 + g * 4] = w0;
    *(u16x4*)&Plds[w][pp][ql * 40 + 16 + g * 4] = w1;
    __syncthreads();
    // P B-frag: lane holds P[q=lane&15][kv_local = g*8 + j]
    s16x8 pf = *(const s16x8*)&Plds[w][pp][ql * 40 + g * 8];
    // V^T A-frags: rows d
    s16x8 vf0 = *(const s16x8*)(vbase + (size_t)ql * 1024 + kv0 + g * 8);
    s16x8 vf1 = *(const s16x8*)(vbase + (size_t)(16 + ql) * 1024 + kv0 + g * 8);
    oacc0 = __builtin_amdgcn_mfma_f32_16x16x32_bf16(vf0, pf, oacc0, 0, 0, 0);
    oacc1 = __builtin_amdgcn_mfma_f32_16x16x32_bf16(vf1, pf, oacc1, 0, 0, 0);
  }
  // full row sum for q = lane&15
  float lf = l_part;
  lf += __shfl_xor(lf, 16);
  lf += __shfl_xor(lf, 32);
  float inv = 1.0f / lf;
  // lane holds O[q=lane&15][d = 16*t2 + g*4 + r]
  unsigned short* op = o + (size_t)qrow * 512 + h * 32;
  u16x4 ov0, ov1;
#pragma unroll
  for (int r = 0; r < 4; ++r) {
    ov0[r] = f2b(oacc0[r] * inv);
    ov1[r] = f2b(oacc1[r] * inv);
  }
  *(u16x4*)(op + g * 4) = ov0;
  *(u16x4*)(op + 16 + g * 4) = ov1;
}

// ---------------- targets pass-through (output 2) ----------------
__global__ void tail_targets(const int* __restrict__ t, float* __restrict__ out) {
  int i = blockIdx.x * 256 + threadIdx.x;
  if (i < 2048) out[33554432 + i] = (float)t[i];
}

extern "C" void kernel_launch(void* const* d_in, const int* in_sizes, int n_in,
                              void* d_out, int out_size, void* d_ws, size_t ws_size,
                              hipStream_t stream) {
  const float* visual   = (const float*)d_in[0];
  const int*   targets  = (const int*)d_in[1];
  const int*   pad_p    = (const int*)d_in[2];
  const float* char_emb = (const float*)d_in[3];
  const float* ln1_g = (const float*)d_in[4];
  const float* ln1_b = (const float*)d_in[5];
  const float* in_proj_w = (const float*)d_in[6];
  const float* in_proj_b = (const float*)d_in[7];
  const float* out_w = (const float*)d_in[8];
  const float* out_b = (const float*)d_in[9];
  const float* fc1_w = (const float*)d_in[10];
  const float* fc1_b = (const float*)d_in[11];
  const float* fc2_w = (const float*)d_in[12];
  const float* fc2_b = (const float*)d_in[13];
  const float* ln2_g = (const float*)d_in[14];
  const float* ln2_b = (const float*)d_in[15];
  const float* ltok  = (const float*)d_in[16];
  const float* rtok  = (const float*)d_in[17];
  const float* q_w   = (const float*)d_in[18];
  const float* q_b   = (const float*)d_in[19];
  const float* kv_w  = (const float*)d_in[20];
  const float* kv_b  = (const float*)d_in[21];
  const float* proj_w = (const float*)d_in[22];
  const float* proj_b = (const float*)d_in[23];
  const float* lnq_g = (const float*)d_in[24];
  const float* lnq_b = (const float*)d_in[25];
  const float* lnkv_g = (const float*)d_in[26];
  const float* lnkv_b = (const float*)d_in[27];
  const float* head_w = (const float*)d_in[28];
  const float* head_b = (const float*)d_in[29];

  // workspace layout (bytes); Kp+VpT (bf16, 67MB) alias the dead encoder region
  char* ws = (char*)d_ws;
  unsigned short* W    = (unsigned short*)ws;                    // 14,680,064 B weights bf16
  float*          X    = (float*)(ws + 14680064ull);             // 25,165,824 B x fp32 12288x512
  unsigned short* KP   = (unsigned short*)(ws + 14680064ull);    // alias: 33,554,432 B Kp + 33,554,432 B VpT
  unsigned short* A1   = (unsigned short*)(ws + 39845888ull);    // 12,582,912 B bf16 12288x512
  unsigned short* B1   = (unsigned short*)(ws + 52428800ull);    // 25,165,824 B bf16 12288x1024
  unsigned short* QKV  = (unsigned short*)(ws + 77594624ull);    // 37,748,736 B bf16 12288x1536
  float*          ENC  = (float*)(ws + 115343360ull);            //  8,388,608 B fp32 4096x512
  unsigned short* VIS  = (unsigned short*)(ws + 123731968ull);   // 33,554,432 B bf16 32768x512
  float*          Q    = (float*)(ws + 157286400ull);            //  8,388,608 B fp32 4096x512
  unsigned short* OC   = (unsigned short*)(ws + 165675008ull);   //  4,194,304 B bf16 4096x512
  unsigned short* FEAT = (unsigned short*)(ws + 169869312ull);   //  4,194,304 B bf16 4096x512
  unsigned short* LNQ  = (unsigned short*)(ws + 174063616ull);   //  4,194,304 B bf16 4096x512
  unsigned short* VPT  = KP + 16777216u;

  unsigned short* Wip   = W;
  unsigned short* Wout  = W + 786432;
  unsigned short* Wfc1  = W + 1048576;
  unsigned short* Wfc2  = W + 1572864;
  unsigned short* Wq    = W + 2097152;
  unsigned short* Wkv   = W + 2359296;
  unsigned short* Wproj = W + 2883584;
  unsigned short* Whead = W + 3145728;

  auto cvt = [&](const float* s, unsigned short* d, int n) {
    cvt_f32_bf16<<<dim3((n / 4 + 255) / 256), dim3(256), 0, stream>>>(s, d, n / 4);
  };
  cvt(in_proj_w, Wip, 786432);
  cvt(out_w, Wout, 262144);
  cvt(fc1_w, Wfc1, 524288);
  cvt(fc2_w, Wfc2, 524288);
  cvt(q_w, Wq, 262144);
  cvt(kv_w, Wkv, 524288);
  cvt(proj_w, Wproj, 262144);
  cvt(head_w, Whead, 4194304);

  // ---- encoders (left+right batched, M=12288) ----
  embed_k<<<dim3(6144), dim3(256), 0, stream>>>(targets, pad_p, char_emb, ltok, rtok, X);
  ln_rows<<<dim3(3072), dim3(256), 0, stream>>>(X, ln1_g, ln1_b, A1, 12288);
  gemm_bt<0,0,1,0><<<dim3(12, 96), dim3(256), 0, stream>>>(A1, Wip, in_proj_b, nullptr, QKV, 12288, 1536, 512);
  winattn<<<dim3(768), dim3(256), 0, stream>>>(QKV, B1);
  gemm_bt<1,0,0,0><<<dim3(4, 96), dim3(256), 0, stream>>>(B1, Wout, out_b, X, X, 12288, 512, 512);
  ln_rows<<<dim3(3072), dim3(256), 0, stream>>>(X, ln2_g, ln2_b, A1, 12288);
  gemm_bt<0,1,1,0><<<dim3(8, 96), dim3(256), 0, stream>>>(A1, Wfc1, fc1_b, nullptr, B1, 12288, 1024, 512);
  gemm_bt<1,0,0,0><<<dim3(4, 96), dim3(256), 0, stream>>>(B1, Wfc2, fc2_b, X, X, 12288, 512, 1024);
  mean3<<<dim3(2048), dim3(256), 0, stream>>>(X, ENC);

  // ---- cross attention (kv shared by both sides; encoder buffers now dead) ----
  ln_rows<<<dim3(8192), dim3(256), 0, stream>>>(visual, lnkv_g, lnkv_b, VIS, 32768);
  gemm_bt<0,0,1,1><<<dim3(8, 256), dim3(256), 0, stream>>>(VIS, Wkv, kv_b, nullptr, KP, 32768, 1024, 512);
  ln_rows<<<dim3(1024), dim3(256), 0, stream>>>(ENC, lnq_g, lnq_b, LNQ, 4096);
  gemm_bt<0,0,0,0><<<dim3(4, 32), dim3(256), 0, stream>>>(LNQ, Wq, q_b, nullptr, Q, 4096, 512, 512);
  crossattn_mfma<<<dim3(1024), dim3(256), 0, stream>>>(Q, KP, VPT, OC);
  gemm_bt<1,0,1,0><<<dim3(4, 32), dim3(256), 0, stream>>>(OC, Wproj, proj_b, ENC, FEAT, 4096, 512, 512);

  // ---- head -> d_out (rows 0..2047 = sgm_left, 2048..4095 = sgm_right) ----
  gemm_bt<0,0,0,0><<<dim3(64, 32), dim3(256), 0, stream>>>(FEAT, Whead, head_b, nullptr, (float*)d_out, 4096, 8192, 512);
  tail_targets<<<dim3(8), dim3(256), 0, stream>>>(targets, (float*)d_out);
}

// Round 3
// 446.254 us; speedup vs baseline: 3.8062x; 1.0687x over previous
//
#include <hip/hip_runtime.h>
#include <hip/hip_bf16.h>
#include <cstdint>
#include <cstddef>

// SGM fused pipeline, MI355X gfx950.
// Shapes: B=32 L=64 N=1024 D=512 C=8192 WS=3 NH=16 HD=32 HID=1024
// Encoder rows M=12288 (side*6144 + pos*3 + w), cross rows 4096 (side*2048+pos).

typedef __attribute__((ext_vector_type(8))) short s16x8;
typedef __attribute__((ext_vector_type(8))) unsigned short u16x8;
typedef __attribute__((ext_vector_type(4))) unsigned short u16x4;
typedef __attribute__((ext_vector_type(4))) float f32x4;

__device__ __forceinline__ float b2f(unsigned short u) {
  union { unsigned int i; float f; } c; c.i = ((unsigned int)u) << 16; return c.f;
}
__device__ __forceinline__ unsigned short f2b(float f) {
  union { float f; unsigned int i; } c; c.f = f;
  unsigned int x = c.i;
  return (unsigned short)((x + 0x7FFFu + ((x >> 16) & 1u)) >> 16); // RNE, no NaN in this net
}

// async global->LDS, 16B per lane; LDS dest is wave-uniform base + lane*16
#define GLOAD16(gp, lp)                                                        \
  __builtin_amdgcn_global_load_lds(                                           \
      (const __attribute__((address_space(1))) void*)(gp),                    \
      (__attribute__((address_space(3))) void*)(lp), 16, 0, 0)

// ---------------- fp32 -> bf16 convert (weights) ----------------
__global__ void cvt_f32_bf16(const float* __restrict__ s, unsigned short* __restrict__ d, int n4) {
  int i = blockIdx.x * 256 + threadIdx.x;
  if (i >= n4) return;
  float4 v = ((const float4*)s)[i];
  u16x4 o; o[0] = f2b(v.x); o[1] = f2b(v.y); o[2] = f2b(v.z); o[3] = f2b(v.w);
  *(u16x4*)(d + (size_t)i * 4) = o;
}

// ---------------- embedding + token add ----------------
__global__ void embed_k(const int* __restrict__ targets, const int* __restrict__ pad_p,
                        const float* __restrict__ ce, const float* __restrict__ ltok,
                        const float* __restrict__ rtok, float* __restrict__ x) {
  int idx = blockIdx.x * 256 + threadIdx.x;   // float4 index, 12288*128 total
  if (idx >= 12288 * 128) return;
  int row = idx >> 7, d4 = idx & 127;
  int side = row >= 6144;
  int rem = row - side * 6144;
  int pos = rem / 3, w = rem - pos * 3;
  int b = pos >> 6, l = pos & 63;
  int id;
  if (!side) { int ti = l + w - 3; id = (ti >= 0) ? targets[(b << 6) + ti] : *pad_p; }
  else       { int ti = l + w + 1; id = (ti < 64) ? targets[(b << 6) + ti] : *pad_p; }
  float4 cv = ((const float4*)ce)[(size_t)id * 128 + d4];
  float4 tv = ((const float4*)(side ? rtok : ltok))[d4];
  float4 o; o.x = cv.x + tv.x; o.y = cv.y + tv.y; o.z = cv.z + tv.z; o.w = cv.w + tv.w;
  ((float4*)x)[idx] = o;
}

// ---------------- LayerNorm (D=512, fp32 in -> bf16 out), one wave per row ----------------
__global__ __launch_bounds__(256) void ln_rows(const float* __restrict__ in,
    const float* __restrict__ g, const float* __restrict__ b,
    unsigned short* __restrict__ out, int M) {
  int row = blockIdx.x * 4 + (threadIdx.x >> 6);
  int lane = threadIdx.x & 63;
  const float* rp = in + (size_t)row * 512;
  float4 v0 = ((const float4*)rp)[lane * 2];
  float4 v1 = ((const float4*)rp)[lane * 2 + 1];
  float vv[8] = {v0.x, v0.y, v0.z, v0.w, v1.x, v1.y, v1.z, v1.w};
  float s = 0.f, ss = 0.f;
#pragma unroll
  for (int j = 0; j < 8; ++j) { s += vv[j]; ss += vv[j] * vv[j]; }
#pragma unroll
  for (int o = 1; o < 64; o <<= 1) { s += __shfl_xor(s, o); ss += __shfl_xor(ss, o); }
  float mean = s * (1.0f / 512.0f);
  float var = ss * (1.0f / 512.0f) - mean * mean;
  float inv = rsqrtf(var + 1e-5f);
  int c = lane * 8;
  u16x8 o8;
#pragma unroll
  for (int j = 0; j < 8; ++j) o8[j] = f2b((vv[j] - mean) * inv * g[c + j] + b[c + j]);
  *(u16x8*)(out + (size_t)row * 512 + c) = o8;
}

// ---------------- bf16 MFMA GEMM (m97 structure): C = A @ Bt^T + bias (+res) (gelu?) ----
// 128x128 tile, BK=32, linear LDS [128][32], global_load_lds dwordx4 staging,
// 4 waves each own 64x64, bijective XCD block swizzle.
// KVT=1: N=1024 KV projection; writes K to Kp[b][h][n][32] and V^T to VpT[b][h][d][n].
template<int RES, int GELU, int OUTBF, int KVT>
__global__ __launch_bounds__(256) void gemm_bt(
    const unsigned short* __restrict__ A, const unsigned short* __restrict__ Bt,
    const float* __restrict__ bias, const float* __restrict__ res,
    void* __restrict__ outp, int M, int N, int K) {
  __shared__ unsigned short sA[128 * 32];
  __shared__ unsigned short sB[128 * 32];
  const int tid = threadIdx.x;
  // XCD-aware bijective swizzle (all launches have nwg % 8 == 0)
  const int nbx = gridDim.x;
  int id = blockIdx.y * nbx + blockIdx.x;
  {
    const int nwg = nbx * gridDim.y;
    if ((nwg & 7) == 0) id = (id & 7) * (nwg >> 3) + (id >> 3);
  }
  const int bm = (id / nbx) * 128, bn = (id % nbx) * 128;
  const int wave = tid >> 6, lane = tid & 63;
  const int wr = (wave >> 1) * 64, wc = (wave & 1) * 64;
  const int lrow = lane & 15, lk = (lane >> 4) * 8;
  f32x4 acc[4][4] = {};
  // staging: wave w covers tile rows [w*32, w*32+32); lane l -> row w*32+c*16+l/4, col (l&3)*8
  const int srow = lane >> 2;
  const int scol = (lane & 3) * 8;
  const unsigned short* gA0 = A + (size_t)(bm + wave * 32 + srow) * K + scol;
  const unsigned short* gA1 = gA0 + (size_t)16 * K;
  const unsigned short* gB0 = Bt + (size_t)(bn + wave * 32 + srow) * K + scol;
  const unsigned short* gB1 = gB0 + (size_t)16 * K;
  unsigned short* lA0 = &sA[wave * 1024];
  unsigned short* lA1 = &sA[wave * 1024 + 512];
  unsigned short* lB0 = &sB[wave * 1024];
  unsigned short* lB1 = &sB[wave * 1024 + 512];
  for (int k0 = 0; k0 < K; k0 += 32) {
    __syncthreads();
    GLOAD16(gA0 + k0, lA0);
    GLOAD16(gA1 + k0, lA1);
    GLOAD16(gB0 + k0, lB0);
    GLOAD16(gB1 + k0, lB1);
    __syncthreads();
    s16x8 av[4], bv[4];
#pragma unroll
    for (int m = 0; m < 4; ++m) av[m] = *(const s16x8*)&sA[(wr + m * 16 + lrow) * 32 + lk];
#pragma unroll
    for (int n = 0; n < 4; ++n) bv[n] = *(const s16x8*)&sB[(wc + n * 16 + lrow) * 32 + lk];
#pragma unroll
    for (int m = 0; m < 4; ++m)
#pragma unroll
      for (int n = 0; n < 4; ++n)
        acc[m][n] = __builtin_amdgcn_mfma_f32_16x16x32_bf16(av[m], bv[n], acc[m][n], 0, 0, 0);
  }
  const int orow0 = bm + wr + (lane >> 4) * 4;
  const int ocol0 = bn + wc + (lane & 15);
#pragma unroll
  for (int m = 0; m < 4; ++m) {
#pragma unroll
    for (int n = 0; n < 4; ++n) {
#pragma unroll
      for (int r = 0; r < 4; ++r) {
        int row = orow0 + m * 16 + r;
        int col = ocol0 + n * 16;
        float v = acc[m][n][r] + bias[col];
        if (KVT) {
          // row = b*1024 + n_vis ; col<512 -> K head block, col>=512 -> V^T
          int bb = row >> 10, nn = row & 1023;
          unsigned short* Kp = (unsigned short*)outp;
          unsigned short* VpT = Kp + 16777216u;
          if (col < 512) {
            int hh = col >> 5, dd = col & 31;
            Kp[(((size_t)(bb * 16 + hh)) * 1024 + nn) * 32 + dd] = f2b(v);
          } else {
            int cc = col - 512, hh = cc >> 5, dd = cc & 31;
            VpT[(((size_t)(bb * 16 + hh)) * 32 + dd) * 1024 + nn] = f2b(v);
          }
        } else {
          if (GELU) v = 0.5f * v * (1.0f + erff(v * 0.70710678118654752f));
          if (RES) v += res[(size_t)row * N + col];
          if (OUTBF) ((unsigned short*)outp)[(size_t)row * N + col] = f2b(v);
          else       ((float*)outp)[(size_t)row * N + col] = v;
        }
      }
    }
  }
}

// ---------------- windowed (WS=3) attention, thread per (side-pos, head, q-row) ----------------
__global__ __launch_bounds__(256) void winattn(const unsigned short* __restrict__ qkv,
                                               unsigned short* __restrict__ o) {
  int g = blockIdx.x * 256 + threadIdx.x;
  if (g >= 4096 * 48) return;
  int i = g % 3;
  int t = g / 3;
  int h = t & 15;
  int sp = t >> 4;
  const unsigned short* base = qkv + (size_t)sp * 4608 + h * 32;
  float qv[32];
  {
    const u16x8* qp = (const u16x8*)(base + (size_t)i * 1536);
#pragma unroll
    for (int c = 0; c < 4; ++c) {
      u16x8 v = qp[c];
#pragma unroll
      for (int j = 0; j < 8; ++j) qv[c * 8 + j] = b2f(v[j]);
    }
  }
  float s[3];
#pragma unroll
  for (int j3 = 0; j3 < 3; ++j3) {
    const u16x8* kp = (const u16x8*)(base + (size_t)j3 * 1536 + 512);
    float acc = 0.f;
#pragma unroll
    for (int c = 0; c < 4; ++c) {
      u16x8 v = kp[c];
#pragma unroll
      for (int j = 0; j < 8; ++j) acc += qv[c * 8 + j] * b2f(v[j]);
    }
    s[j3] = acc * 0.17677669529663687f;
  }
  float mx = fmaxf(s[0], fmaxf(s[1], s[2]));
  float e0 = __expf(s[0] - mx), e1 = __expf(s[1] - mx), e2 = __expf(s[2] - mx);
  float inv = 1.0f / (e0 + e1 + e2);
  float a0 = e0 * inv, a1 = e1 * inv, a2 = e2 * inv;
  unsigned short* op = o + (size_t)(sp * 3 + i) * 512 + h * 32;
  const u16x8* v0p = (const u16x8*)(base + 1024);
  const u16x8* v1p = (const u16x8*)(base + 1536 + 1024);
  const u16x8* v2p = (const u16x8*)(base + 3072 + 1024);
#pragma unroll
  for (int c = 0; c < 4; ++c) {
    u16x8 x0 = v0p[c], x1 = v1p[c], x2 = v2p[c];
    u16x8 ov;
#pragma unroll
    for (int j = 0; j < 8; ++j)
      ov[j] = f2b(a0 * b2f(x0[j]) + a1 * b2f(x1[j]) + a2 * b2f(x2[j]));
    *(u16x8*)(op + c * 8) = ov;
  }
}

// ---------------- mean over WS=3 ----------------
__global__ void mean3(const float* __restrict__ x, float* __restrict__ enc) {
  int i = blockIdx.x * 256 + threadIdx.x;   // float4 index, 4096*128
  if (i >= 4096 * 128) return;
  int p = i >> 7, d4 = i & 127;
  const float4* xp = (const float4*)x;
  float4 a = xp[(size_t)(p * 3 + 0) * 128 + d4];
  float4 b = xp[(size_t)(p * 3 + 1) * 128 + d4];
  float4 c = xp[(size_t)(p * 3 + 2) * 128 + d4];
  float4 o;
  o.x = (a.x + b.x + c.x) * (1.0f / 3.0f);
  o.y = (a.y + b.y + c.y) * (1.0f / 3.0f);
  o.z = (a.z + b.z + c.z) * (1.0f / 3.0f);
  o.w = (a.w + b.w + c.w) * (1.0f / 3.0f);
  ((float4*)enc)[i] = o;
}

// ---------------- cross attention, MFMA flash style ----------------
__global__ __launch_bounds__(256) void crossattn_mfma(const float* __restrict__ q,
    const unsigned short* __restrict__ Kp, const unsigned short* __restrict__ VpT,
    unsigned short* __restrict__ o) {
  __shared__ unsigned short Plds[4][2][16 * 40];
  const int sbh = blockIdx.x;
  const int side = sbh >> 9, b = (sbh >> 4) & 31, h = sbh & 15;
  const int tid = threadIdx.x;
  const int w = tid >> 6, lane = tid & 63;
  const int ql = lane & 15, g = lane >> 4;
  const int qrow = side * 2048 + b * 64 + w * 16 + ql;
  const float SC = 0.17677669529663687f;
  s16x8 qf;
  {
    const float* qp = q + (size_t)qrow * 512 + h * 32 + g * 8;
    float4 qa = ((const float4*)qp)[0];
    float4 qb4 = ((const float4*)qp)[1];
    qf[0] = (short)f2b(qa.x * SC); qf[1] = (short)f2b(qa.y * SC);
    qf[2] = (short)f2b(qa.z * SC); qf[3] = (short)f2b(qa.w * SC);
    qf[4] = (short)f2b(qb4.x * SC); qf[5] = (short)f2b(qb4.y * SC);
    qf[6] = (short)f2b(qb4.z * SC); qf[7] = (short)f2b(qb4.w * SC);
  }
  const unsigned short* kbase = Kp + ((size_t)(b * 16 + h) * 1024) * 32;
  const unsigned short* vbase = VpT + ((size_t)(b * 16 + h) * 32) * 1024;
  f32x4 oacc0 = {}, oacc1 = {};
  float m_run = -1e30f, l_part = 0.f;
  for (int kv0 = 0; kv0 < 1024; kv0 += 32) {
    const int pp = (kv0 >> 5) & 1;
    s16x8 kf0 = *(const s16x8*)(kbase + (size_t)(kv0 + ql) * 32 + g * 8);
    s16x8 kf1 = *(const s16x8*)(kbase + (size_t)(kv0 + 16 + ql) * 32 + g * 8);
    f32x4 z = {0.f, 0.f, 0.f, 0.f};
    f32x4 s0 = __builtin_amdgcn_mfma_f32_16x16x32_bf16(kf0, qf, z, 0, 0, 0);
    f32x4 s1 = __builtin_amdgcn_mfma_f32_16x16x32_bf16(kf1, qf, z, 0, 0, 0);
    float cm = fmaxf(fmaxf(fmaxf(s0[0], s0[1]), fmaxf(s0[2], s0[3])),
                     fmaxf(fmaxf(s1[0], s1[1]), fmaxf(s1[2], s1[3])));
    cm = fmaxf(cm, __shfl_xor(cm, 16));
    cm = fmaxf(cm, __shfl_xor(cm, 32));
    float m_new = fmaxf(m_run, cm);
    float corr = __expf(m_run - m_new);
    m_run = m_new;
    float p0[4], p1[4], ps = 0.f;
#pragma unroll
    for (int r = 0; r < 4; ++r) {
      p0[r] = __expf(s0[r] - m_new);
      p1[r] = __expf(s1[r] - m_new);
      ps += p0[r] + p1[r];
    }
    l_part = l_part * corr + ps;
    oacc0 *= corr; oacc1 *= corr;
    u16x4 w0, w1;
#pragma unroll
    for (int r = 0; r < 4; ++r) { w0[r] = f2b(p0[r]); w1[r] = f2b(p1[r]); }
    *(u16x4*)&Plds[w][pp][ql * 40 + g * 4] = w0;
    *(u16x4*)&Plds[w][pp][ql * 40 + 16 + g * 4] = w1;
    __syncthreads();
    s16x8 pf = *(const s16x8*)&Plds[w][pp][ql * 40 + g * 8];
    s16x8 vf0 = *(const s16x8*)(vbase + (size_t)ql * 1024 + kv0 + g * 8);
    s16x8 vf1 = *(const s16x8*)(vbase + (size_t)(16 + ql) * 1024 + kv0 + g * 8);
    oacc0 = __builtin_amdgcn_mfma_f32_16x16x32_bf16(vf0, pf, oacc0, 0, 0, 0);
    oacc1 = __builtin_amdgcn_mfma_f32_16x16x32_bf16(vf1, pf, oacc1, 0, 0, 0);
  }
  float lf = l_part;
  lf += __shfl_xor(lf, 16);
  lf += __shfl_xor(lf, 32);
  float inv = 1.0f / lf;
  unsigned short* op = o + (size_t)qrow * 512 + h * 32;
  u16x4 ov0, ov1;
#pragma unroll
  for (int r = 0; r < 4; ++r) {
    ov0[r] = f2b(oacc0[r] * inv);
    ov1[r] = f2b(oacc1[r] * inv);
  }
  *(u16x4*)(op + g * 4) = ov0;
  *(u16x4*)(op + 16 + g * 4) = ov1;
}

// ---------------- targets pass-through (output 2) ----------------
__global__ void tail_targets(const int* __restrict__ t, float* __restrict__ out) {
  int i = blockIdx.x * 256 + threadIdx.x;
  if (i < 2048) out[33554432 + i] = (float)t[i];
}

extern "C" void kernel_launch(void* const* d_in, const int* in_sizes, int n_in,
                              void* d_out, int out_size, void* d_ws, size_t ws_size,
                              hipStream_t stream) {
  const float* visual   = (const float*)d_in[0];
  const int*   targets  = (const int*)d_in[1];
  const int*   pad_p    = (const int*)d_in[2];
  const float* char_emb = (const float*)d_in[3];
  const float* ln1_g = (const float*)d_in[4];
  const float* ln1_b = (const float*)d_in[5];
  const float* in_proj_w = (const float*)d_in[6];
  const float* in_proj_b = (const float*)d_in[7];
  const float* out_w = (const float*)d_in[8];
  const float* out_b = (const float*)d_in[9];
  const float* fc1_w = (const float*)d_in[10];
  const float* fc1_b = (const float*)d_in[11];
  const float* fc2_w = (const float*)d_in[12];
  const float* fc2_b = (const float*)d_in[13];
  const float* ln2_g = (const float*)d_in[14];
  const float* ln2_b = (const float*)d_in[15];
  const float* ltok  = (const float*)d_in[16];
  const float* rtok  = (const float*)d_in[17];
  const float* q_w   = (const float*)d_in[18];
  const float* q_b   = (const float*)d_in[19];
  const float* kv_w  = (const float*)d_in[20];
  const float* kv_b  = (const float*)d_in[21];
  const float* proj_w = (const float*)d_in[22];
  const float* proj_b = (const float*)d_in[23];
  const float* lnq_g = (const float*)d_in[24];
  const float* lnq_b = (const float*)d_in[25];
  const float* lnkv_g = (const float*)d_in[26];
  const float* lnkv_b = (const float*)d_in[27];
  const float* head_w = (const float*)d_in[28];
  const float* head_b = (const float*)d_in[29];

  // workspace layout (bytes); Kp+VpT (bf16, 67MB) alias the dead encoder region
  char* ws = (char*)d_ws;
  unsigned short* W    = (unsigned short*)ws;                    // 14,680,064 B weights bf16
  float*          X    = (float*)(ws + 14680064ull);             // 25,165,824 B x fp32 12288x512
  unsigned short* KP   = (unsigned short*)(ws + 14680064ull);    // alias: 33,554,432 B Kp + 33,554,432 B VpT
  unsigned short* A1   = (unsigned short*)(ws + 39845888ull);    // 12,582,912 B bf16 12288x512
  unsigned short* B1   = (unsigned short*)(ws + 52428800ull);    // 25,165,824 B bf16 12288x1024
  unsigned short* QKV  = (unsigned short*)(ws + 77594624ull);    // 37,748,736 B bf16 12288x1536
  float*          ENC  = (float*)(ws + 115343360ull);            //  8,388,608 B fp32 4096x512
  unsigned short* VIS  = (unsigned short*)(ws + 123731968ull);   // 33,554,432 B bf16 32768x512
  float*          Q    = (float*)(ws + 157286400ull);            //  8,388,608 B fp32 4096x512
  unsigned short* OC   = (unsigned short*)(ws + 165675008ull);   //  4,194,304 B bf16 4096x512
  unsigned short* FEAT = (unsigned short*)(ws + 169869312ull);   //  4,194,304 B bf16 4096x512
  unsigned short* LNQ  = (unsigned short*)(ws + 174063616ull);   //  4,194,304 B bf16 4096x512
  unsigned short* VPT  = KP + 16777216u;

  unsigned short* Wip   = W;
  unsigned short* Wout  = W + 786432;
  unsigned short* Wfc1  = W + 1048576;
  unsigned short* Wfc2  = W + 1572864;
  unsigned short* Wq    = W + 2097152;
  unsigned short* Wkv   = W + 2359296;
  unsigned short* Wproj = W + 2883584;
  unsigned short* Whead = W + 3145728;

  auto cvt = [&](const float* s, unsigned short* d, int n) {
    cvt_f32_bf16<<<dim3((n / 4 + 255) / 256), dim3(256), 0, stream>>>(s, d, n / 4);
  };
  cvt(in_proj_w, Wip, 786432);
  cvt(out_w, Wout, 262144);
  cvt(fc1_w, Wfc1, 524288);
  cvt(fc2_w, Wfc2, 524288);
  cvt(q_w, Wq, 262144);
  cvt(kv_w, Wkv, 524288);
  cvt(proj_w, Wproj, 262144);
  cvt(head_w, Whead, 4194304);

  // ---- encoders (left+right batched, M=12288) ----
  embed_k<<<dim3(6144), dim3(256), 0, stream>>>(targets, pad_p, char_emb, ltok, rtok, X);
  ln_rows<<<dim3(3072), dim3(256), 0, stream>>>(X, ln1_g, ln1_b, A1, 12288);
  gemm_bt<0,0,1,0><<<dim3(12, 96), dim3(256), 0, stream>>>(A1, Wip, in_proj_b, nullptr, QKV, 12288, 1536, 512);
  winattn<<<dim3(768), dim3(256), 0, stream>>>(QKV, B1);
  gemm_bt<1,0,0,0><<<dim3(4, 96), dim3(256), 0, stream>>>(B1, Wout, out_b, X, X, 12288, 512, 512);
  ln_rows<<<dim3(3072), dim3(256), 0, stream>>>(X, ln2_g, ln2_b, A1, 12288);
  gemm_bt<0,1,1,0><<<dim3(8, 96), dim3(256), 0, stream>>>(A1, Wfc1, fc1_b, nullptr, B1, 12288, 1024, 512);
  gemm_bt<1,0,0,0><<<dim3(4, 96), dim3(256), 0, stream>>>(B1, Wfc2, fc2_b, X, X, 12288, 512, 1024);
  mean3<<<dim3(2048), dim3(256), 0, stream>>>(X, ENC);

  // ---- cross attention (kv shared by both sides; encoder buffers now dead) ----
  ln_rows<<<dim3(8192), dim3(256), 0, stream>>>(visual, lnkv_g, lnkv_b, VIS, 32768);
  gemm_bt<0,0,1,1><<<dim3(8, 256), dim3(256), 0, stream>>>(VIS, Wkv, kv_b, nullptr, KP, 32768, 1024, 512);
  ln_rows<<<dim3(1024), dim3(256), 0, stream>>>(ENC, lnq_g, lnq_b, LNQ, 4096);
  gemm_bt<0,0,0,0><<<dim3(4, 32), dim3(256), 0, stream>>>(LNQ, Wq, q_b, nullptr, Q, 4096, 512, 512);
  crossattn_mfma<<<dim3(1024), dim3(256), 0, stream>>>(Q, KP, VPT, OC);
  gemm_bt<1,0,1,0><<<dim3(4, 32), dim3(256), 0, stream>>>(OC, Wproj, proj_b, ENC, FEAT, 4096, 512, 512);

  // ---- head -> d_out (rows 0..2047 = sgm_left, 2048..4095 = sgm_right) ----
  gemm_bt<0,0,0,0><<<dim3(64, 32), dim3(256), 0, stream>>>(FEAT, Whead, head_b, nullptr, (float*)d_out, 4096, 8192, 512);
  tail_targets<<<dim3(8), dim3(256), 0, stream>>>(targets, (float*)d_out);
}

// Round 4
// 427.282 us; speedup vs baseline: 3.9752x; 1.0444x over previous
//
#include <hip/hip_runtime.h>
#include <hip/hip_bf16.h>
#include <cstdint>
#include <cstddef>

// SGM fused pipeline, MI355X gfx950.
// Shapes: B=32 L=64 N=1024 D=512 C=8192 WS=3 NH=16 HD=32 HID=1024
// Encoder rows M=12288 (side*6144 + pos*3 + w), cross rows 4096 (side*2048+pos).

typedef __attribute__((ext_vector_type(8))) short s16x8;
typedef __attribute__((ext_vector_type(8))) unsigned short u16x8;
typedef __attribute__((ext_vector_type(4))) unsigned short u16x4;
typedef __attribute__((ext_vector_type(4))) float f32x4;

__device__ __forceinline__ float b2f(unsigned short u) {
  union { unsigned int i; float f; } c; c.i = ((unsigned int)u) << 16; return c.f;
}
__device__ __forceinline__ unsigned short f2b(float f) {
  union { float f; unsigned int i; } c; c.f = f;
  unsigned int x = c.i;
  return (unsigned short)((x + 0x7FFFu + ((x >> 16) & 1u)) >> 16); // RNE, no NaN in this net
}

// async global->LDS, 16B per lane; LDS dest is wave-uniform base + lane*16
#define GLOAD16(gp, lp)                                                        \
  __builtin_amdgcn_global_load_lds(                                           \
      (const __attribute__((address_space(1))) void*)(gp),                    \
      (__attribute__((address_space(3))) void*)(lp), 16, 0, 0)

// ---------------- fp32 -> bf16 convert (weights) ----------------
__global__ void cvt_f32_bf16(const float* __restrict__ s, unsigned short* __restrict__ d, int n4) {
  int i = blockIdx.x * 256 + threadIdx.x;
  if (i >= n4) return;
  float4 v = ((const float4*)s)[i];
  u16x4 o; o[0] = f2b(v.x); o[1] = f2b(v.y); o[2] = f2b(v.z); o[3] = f2b(v.w);
  *(u16x4*)(d + (size_t)i * 4) = o;
}

// ---------------- embedding + token add ----------------
__global__ void embed_k(const int* __restrict__ targets, const int* __restrict__ pad_p,
                        const float* __restrict__ ce, const float* __restrict__ ltok,
                        const float* __restrict__ rtok, float* __restrict__ x) {
  int idx = blockIdx.x * 256 + threadIdx.x;   // float4 index, 12288*128 total
  if (idx >= 12288 * 128) return;
  int row = idx >> 7, d4 = idx & 127;
  int side = row >= 6144;
  int rem = row - side * 6144;
  int pos = rem / 3, w = rem - pos * 3;
  int b = pos >> 6, l = pos & 63;
  int id;
  if (!side) { int ti = l + w - 3; id = (ti >= 0) ? targets[(b << 6) + ti] : *pad_p; }
  else       { int ti = l + w + 1; id = (ti < 64) ? targets[(b << 6) + ti] : *pad_p; }
  float4 cv = ((const float4*)ce)[(size_t)id * 128 + d4];
  float4 tv = ((const float4*)(side ? rtok : ltok))[d4];
  float4 o; o.x = cv.x + tv.x; o.y = cv.y + tv.y; o.z = cv.z + tv.z; o.w = cv.w + tv.w;
  ((float4*)x)[idx] = o;
}

// ---------------- LayerNorm (D=512, fp32 in -> bf16 out), one wave per row ----------------
__global__ __launch_bounds__(256) void ln_rows(const float* __restrict__ in,
    const float* __restrict__ g, const float* __restrict__ b,
    unsigned short* __restrict__ out, int M) {
  int row = blockIdx.x * 4 + (threadIdx.x >> 6);
  int lane = threadIdx.x & 63;
  const float* rp = in + (size_t)row * 512;
  float4 v0 = ((const float4*)rp)[lane * 2];
  float4 v1 = ((const float4*)rp)[lane * 2 + 1];
  float vv[8] = {v0.x, v0.y, v0.z, v0.w, v1.x, v1.y, v1.z, v1.w};
  float s = 0.f, ss = 0.f;
#pragma unroll
  for (int j = 0; j < 8; ++j) { s += vv[j]; ss += vv[j] * vv[j]; }
#pragma unroll
  for (int o = 1; o < 64; o <<= 1) { s += __shfl_xor(s, o); ss += __shfl_xor(ss, o); }
  float mean = s * (1.0f / 512.0f);
  float var = ss * (1.0f / 512.0f) - mean * mean;
  float inv = rsqrtf(var + 1e-5f);
  int c = lane * 8;
  u16x8 o8;
#pragma unroll
  for (int j = 0; j < 8; ++j) o8[j] = f2b((vv[j] - mean) * inv * g[c + j] + b[c + j]);
  *(u16x8*)(out + (size_t)row * 512 + c) = o8;
}

// ---------------- bf16 MFMA GEMM, 2-phase double-buffered (T3-min) ----------------
// 128x128 tile, BK=32, linear LDS [2][128][32], global_load_lds dwordx4 staging
// issued one K-tile ahead (loads in flight across ds_read+MFMA), one barrier/step.
// 4 waves each own 64x64. Bijective XCD block swizzle.
// KVT=1: N=1024 KV projection; writes K to Kp[b][h][n][32] and V^T to VpT[b][h][d][n].
template<int RES, int GELU, int OUTBF, int KVT>
__global__ __launch_bounds__(256) void gemm_bt(
    const unsigned short* __restrict__ A, const unsigned short* __restrict__ Bt,
    const float* __restrict__ bias, const float* __restrict__ res,
    void* __restrict__ outp, int M, int N, int K) {
  __shared__ unsigned short sA[2][128 * 32];
  __shared__ unsigned short sB[2][128 * 32];
  const int tid = threadIdx.x;
  // XCD-aware bijective swizzle (all launches have nwg % 8 == 0)
  const int nbx = gridDim.x;
  int id = blockIdx.y * nbx + blockIdx.x;
  {
    const int nwg = nbx * gridDim.y;
    if ((nwg & 7) == 0) id = (id & 7) * (nwg >> 3) + (id >> 3);
  }
  const int bm = (id / nbx) * 128, bn = (id % nbx) * 128;
  const int wave = tid >> 6, lane = tid & 63;
  const int wr = (wave >> 1) * 64, wc = (wave & 1) * 64;
  const int lrow = lane & 15, lk = (lane >> 4) * 8;
  f32x4 acc[4][4] = {};
  // staging: wave w covers tile rows [w*32, w*32+32); lane l -> row w*32+l/4, col (l&3)*8
  const int srow = lane >> 2;
  const int scol = (lane & 3) * 8;
  const unsigned short* gA0 = A + (size_t)(bm + wave * 32 + srow) * K + scol;
  const unsigned short* gA1 = gA0 + (size_t)16 * K;
  const unsigned short* gB0 = Bt + (size_t)(bn + wave * 32 + srow) * K + scol;
  const unsigned short* gB1 = gB0 + (size_t)16 * K;
  const int lbase = wave * 1024;
  // prologue: stage K-tile 0 into buffer 0
  GLOAD16(gA0, &sA[0][lbase]);
  GLOAD16(gA1, &sA[0][lbase + 512]);
  GLOAD16(gB0, &sB[0][lbase]);
  GLOAD16(gB1, &sB[0][lbase + 512]);
  __syncthreads();   // compiler emits vmcnt(0) lgkmcnt(0) before s_barrier
  int cur = 0;
  for (int k0 = 0; k0 < K; k0 += 32) {
    const int nxt = cur ^ 1;
    if (k0 + 32 < K) {             // issue next-tile loads BEFORE compute (in flight)
      GLOAD16(gA0 + k0 + 32, &sA[nxt][lbase]);
      GLOAD16(gA1 + k0 + 32, &sA[nxt][lbase + 512]);
      GLOAD16(gB0 + k0 + 32, &sB[nxt][lbase]);
      GLOAD16(gB1 + k0 + 32, &sB[nxt][lbase + 512]);
    }
    s16x8 av[4], bv[4];
#pragma unroll
    for (int m = 0; m < 4; ++m) av[m] = *(const s16x8*)&sA[cur][(wr + m * 16 + lrow) * 32 + lk];
#pragma unroll
    for (int n = 0; n < 4; ++n) bv[n] = *(const s16x8*)&sB[cur][(wc + n * 16 + lrow) * 32 + lk];
#pragma unroll
    for (int m = 0; m < 4; ++m)
#pragma unroll
      for (int n = 0; n < 4; ++n)
        acc[m][n] = __builtin_amdgcn_mfma_f32_16x16x32_bf16(av[m], bv[n], acc[m][n], 0, 0, 0);
    __syncthreads();   // drain prefetch (overlapped) + protect buf reuse
    cur = nxt;
  }
  const int orow0 = bm + wr + (lane >> 4) * 4;
  const int ocol0 = bn + wc + (lane & 15);
#pragma unroll
  for (int m = 0; m < 4; ++m) {
#pragma unroll
    for (int n = 0; n < 4; ++n) {
#pragma unroll
      for (int r = 0; r < 4; ++r) {
        int row = orow0 + m * 16 + r;
        int col = ocol0 + n * 16;
        float v = acc[m][n][r] + bias[col];
        if (KVT) {
          // row = b*1024 + n_vis ; col<512 -> K head block, col>=512 -> V^T
          int bb = row >> 10, nn = row & 1023;
          unsigned short* Kp = (unsigned short*)outp;
          unsigned short* VpT = Kp + 16777216u;
          if (col < 512) {
            int hh = col >> 5, dd = col & 31;
            Kp[(((size_t)(bb * 16 + hh)) * 1024 + nn) * 32 + dd] = f2b(v);
          } else {
            int cc = col - 512, hh = cc >> 5, dd = cc & 31;
            VpT[(((size_t)(bb * 16 + hh)) * 32 + dd) * 1024 + nn] = f2b(v);
          }
        } else {
          if (GELU) v = 0.5f * v * (1.0f + erff(v * 0.70710678118654752f));
          if (RES) v += res[(size_t)row * N + col];
          if (OUTBF) ((unsigned short*)outp)[(size_t)row * N + col] = f2b(v);
          else       ((float*)outp)[(size_t)row * N + col] = v;
        }
      }
    }
  }
}

// ---------------- windowed (WS=3) attention, thread per (side-pos, head, q-row) ----------------
__global__ __launch_bounds__(256) void winattn(const unsigned short* __restrict__ qkv,
                                               unsigned short* __restrict__ o) {
  int g = blockIdx.x * 256 + threadIdx.x;
  if (g >= 4096 * 48) return;
  int i = g % 3;
  int t = g / 3;
  int h = t & 15;
  int sp = t >> 4;
  const unsigned short* base = qkv + (size_t)sp * 4608 + h * 32;
  float qv[32];
  {
    const u16x8* qp = (const u16x8*)(base + (size_t)i * 1536);
#pragma unroll
    for (int c = 0; c < 4; ++c) {
      u16x8 v = qp[c];
#pragma unroll
      for (int j = 0; j < 8; ++j) qv[c * 8 + j] = b2f(v[j]);
    }
  }
  float s[3];
#pragma unroll
  for (int j3 = 0; j3 < 3; ++j3) {
    const u16x8* kp = (const u16x8*)(base + (size_t)j3 * 1536 + 512);
    float acc = 0.f;
#pragma unroll
    for (int c = 0; c < 4; ++c) {
      u16x8 v = kp[c];
#pragma unroll
      for (int j = 0; j < 8; ++j) acc += qv[c * 8 + j] * b2f(v[j]);
    }
    s[j3] = acc * 0.17677669529663687f;
  }
  float mx = fmaxf(s[0], fmaxf(s[1], s[2]));
  float e0 = __expf(s[0] - mx), e1 = __expf(s[1] - mx), e2 = __expf(s[2] - mx);
  float inv = 1.0f / (e0 + e1 + e2);
  float a0 = e0 * inv, a1 = e1 * inv, a2 = e2 * inv;
  unsigned short* op = o + (size_t)(sp * 3 + i) * 512 + h * 32;
  const u16x8* v0p = (const u16x8*)(base + 1024);
  const u16x8* v1p = (const u16x8*)(base + 1536 + 1024);
  const u16x8* v2p = (const u16x8*)(base + 3072 + 1024);
#pragma unroll
  for (int c = 0; c < 4; ++c) {
    u16x8 x0 = v0p[c], x1 = v1p[c], x2 = v2p[c];
    u16x8 ov;
#pragma unroll
    for (int j = 0; j < 8; ++j)
      ov[j] = f2b(a0 * b2f(x0[j]) + a1 * b2f(x1[j]) + a2 * b2f(x2[j]));
    *(u16x8*)(op + c * 8) = ov;
  }
}

// ---------------- mean over WS=3 ----------------
__global__ void mean3(const float* __restrict__ x, float* __restrict__ enc) {
  int i = blockIdx.x * 256 + threadIdx.x;   // float4 index, 4096*128
  if (i >= 4096 * 128) return;
  int p = i >> 7, d4 = i & 127;
  const float4* xp = (const float4*)x;
  float4 a = xp[(size_t)(p * 3 + 0) * 128 + d4];
  float4 b = xp[(size_t)(p * 3 + 1) * 128 + d4];
  float4 c = xp[(size_t)(p * 3 + 2) * 128 + d4];
  float4 o;
  o.x = (a.x + b.x + c.x) * (1.0f / 3.0f);
  o.y = (a.y + b.y + c.y) * (1.0f / 3.0f);
  o.z = (a.z + b.z + c.z) * (1.0f / 3.0f);
  o.w = (a.w + b.w + c.w) * (1.0f / 3.0f);
  ((float4*)enc)[i] = o;
}

// ---------------- cross attention, MFMA flash style ----------------
__global__ __launch_bounds__(256) void crossattn_mfma(const float* __restrict__ q,
    const unsigned short* __restrict__ Kp, const unsigned short* __restrict__ VpT,
    unsigned short* __restrict__ o) {
  __shared__ unsigned short Plds[4][2][16 * 40];
  const int sbh = blockIdx.x;
  const int side = sbh >> 9, b = (sbh >> 4) & 31, h = sbh & 15;
  const int tid = threadIdx.x;
  const int w = tid >> 6, lane = tid & 63;
  const int ql = lane & 15, g = lane >> 4;
  const int qrow = side * 2048 + b * 64 + w * 16 + ql;
  const float SC = 0.17677669529663687f;
  s16x8 qf;
  {
    const float* qp = q + (size_t)qrow * 512 + h * 32 + g * 8;
    float4 qa = ((const float4*)qp)[0];
    float4 qb4 = ((const float4*)qp)[1];
    qf[0] = (short)f2b(qa.x * SC); qf[1] = (short)f2b(qa.y * SC);
    qf[2] = (short)f2b(qa.z * SC); qf[3] = (short)f2b(qa.w * SC);
    qf[4] = (short)f2b(qb4.x * SC); qf[5] = (short)f2b(qb4.y * SC);
    qf[6] = (short)f2b(qb4.z * SC); qf[7] = (short)f2b(qb4.w * SC);
  }
  const unsigned short* kbase = Kp + ((size_t)(b * 16 + h) * 1024) * 32;
  const unsigned short* vbase = VpT + ((size_t)(b * 16 + h) * 32) * 1024;
  f32x4 oacc0 = {}, oacc1 = {};
  float m_run = -1e30f, l_part = 0.f;
  for (int kv0 = 0; kv0 < 1024; kv0 += 32) {
    const int pp = (kv0 >> 5) & 1;
    s16x8 kf0 = *(const s16x8*)(kbase + (size_t)(kv0 + ql) * 32 + g * 8);
    s16x8 kf1 = *(const s16x8*)(kbase + (size_t)(kv0 + 16 + ql) * 32 + g * 8);
    f32x4 z = {0.f, 0.f, 0.f, 0.f};
    f32x4 s0 = __builtin_amdgcn_mfma_f32_16x16x32_bf16(kf0, qf, z, 0, 0, 0);
    f32x4 s1 = __builtin_amdgcn_mfma_f32_16x16x32_bf16(kf1, qf, z, 0, 0, 0);
    float cm = fmaxf(fmaxf(fmaxf(s0[0], s0[1]), fmaxf(s0[2], s0[3])),
                     fmaxf(fmaxf(s1[0], s1[1]), fmaxf(s1[2], s1[3])));
    cm = fmaxf(cm, __shfl_xor(cm, 16));
    cm = fmaxf(cm, __shfl_xor(cm, 32));
    float m_new = fmaxf(m_run, cm);
    float corr = __expf(m_run - m_new);
    m_run = m_new;
    float p0[4], p1[4], ps = 0.f;
#pragma unroll
    for (int r = 0; r < 4; ++r) {
      p0[r] = __expf(s0[r] - m_new);
      p1[r] = __expf(s1[r] - m_new);
      ps += p0[r] + p1[r];
    }
    l_part = l_part * corr + ps;
    oacc0 *= corr; oacc1 *= corr;
    u16x4 w0, w1;
#pragma unroll
    for (int r = 0; r < 4; ++r) { w0[r] = f2b(p0[r]); w1[r] = f2b(p1[r]); }
    *(u16x4*)&Plds[w][pp][ql * 40 + g * 4] = w0;
    *(u16x4*)&Plds[w][pp][ql * 40 + 16 + g * 4] = w1;
    __syncthreads();
    s16x8 pf = *(const s16x8*)&Plds[w][pp][ql * 40 + g * 8];
    s16x8 vf0 = *(const s16x8*)(vbase + (size_t)ql * 1024 + kv0 + g * 8);
    s16x8 vf1 = *(const s16x8*)(vbase + (size_t)(16 + ql) * 1024 + kv0 + g * 8);
    oacc0 = __builtin_amdgcn_mfma_f32_16x16x32_bf16(vf0, pf, oacc0, 0, 0, 0);
    oacc1 = __builtin_amdgcn_mfma_f32_16x16x32_bf16(vf1, pf, oacc1, 0, 0, 0);
  }
  float lf = l_part;
  lf += __shfl_xor(lf, 16);
  lf += __shfl_xor(lf, 32);
  float inv = 1.0f / lf;
  unsigned short* op = o + (size_t)qrow * 512 + h * 32;
  u16x4 ov0, ov1;
#pragma unroll
  for (int r = 0; r < 4; ++r) {
    ov0[r] = f2b(oacc0[r] * inv);
    ov1[r] = f2b(oacc1[r] * inv);
  }
  *(u16x4*)(op + g * 4) = ov0;
  *(u16x4*)(op + 16 + g * 4) = ov1;
}

// ---------------- targets pass-through (output 2) ----------------
__global__ void tail_targets(const int* __restrict__ t, float* __restrict__ out) {
  int i = blockIdx.x * 256 + threadIdx.x;
  if (i < 2048) out[33554432 + i] = (float)t[i];
}

extern "C" void kernel_launch(void* const* d_in, const int* in_sizes, int n_in,
                              void* d_out, int out_size, void* d_ws, size_t ws_size,
                              hipStream_t stream) {
  const float* visual   = (const float*)d_in[0];
  const int*   targets  = (const int*)d_in[1];
  const int*   pad_p    = (const int*)d_in[2];
  const float* char_emb = (const float*)d_in[3];
  const float* ln1_g = (const float*)d_in[4];
  const float* ln1_b = (const float*)d_in[5];
  const float* in_proj_w = (const float*)d_in[6];
  const float* in_proj_b = (const float*)d_in[7];
  const float* out_w = (const float*)d_in[8];
  const float* out_b = (const float*)d_in[9];
  const float* fc1_w = (const float*)d_in[10];
  const float* fc1_b = (const float*)d_in[11];
  const float* fc2_w = (const float*)d_in[12];
  const float* fc2_b = (const float*)d_in[13];
  const float* ln2_g = (const float*)d_in[14];
  const float* ln2_b = (const float*)d_in[15];
  const float* ltok  = (const float*)d_in[16];
  const float* rtok  = (const float*)d_in[17];
  const float* q_w   = (const float*)d_in[18];
  const float* q_b   = (const float*)d_in[19];
  const float* kv_w  = (const float*)d_in[20];
  const float* kv_b  = (const float*)d_in[21];
  const float* proj_w = (const float*)d_in[22];
  const float* proj_b = (const float*)d_in[23];
  const float* lnq_g = (const float*)d_in[24];
  const float* lnq_b = (const float*)d_in[25];
  const float* lnkv_g = (const float*)d_in[26];
  const float* lnkv_b = (const float*)d_in[27];
  const float* head_w = (const float*)d_in[28];
  const float* head_b = (const float*)d_in[29];

  // workspace layout (bytes); Kp+VpT (bf16, 67MB) alias the dead encoder region
  char* ws = (char*)d_ws;
  unsigned short* W    = (unsigned short*)ws;                    // 14,680,064 B weights bf16
  float*          X    = (float*)(ws + 14680064ull);             // 25,165,824 B x fp32 12288x512
  unsigned short* KP   = (unsigned short*)(ws + 14680064ull);    // alias: 33,554,432 B Kp + 33,554,432 B VpT
  unsigned short* A1   = (unsigned short*)(ws + 39845888ull);    // 12,582,912 B bf16 12288x512
  unsigned short* B1   = (unsigned short*)(ws + 52428800ull);    // 25,165,824 B bf16 12288x1024
  unsigned short* QKV  = (unsigned short*)(ws + 77594624ull);    // 37,748,736 B bf16 12288x1536
  float*          ENC  = (float*)(ws + 115343360ull);            //  8,388,608 B fp32 4096x512
  unsigned short* VIS  = (unsigned short*)(ws + 123731968ull);   // 33,554,432 B bf16 32768x512
  float*          Q    = (float*)(ws + 157286400ull);            //  8,388,608 B fp32 4096x512
  unsigned short* OC   = (unsigned short*)(ws + 165675008ull);   //  4,194,304 B bf16 4096x512
  unsigned short* FEAT = (unsigned short*)(ws + 169869312ull);   //  4,194,304 B bf16 4096x512
  unsigned short* LNQ  = (unsigned short*)(ws + 174063616ull);   //  4,194,304 B bf16 4096x512
  unsigned short* VPT  = KP + 16777216u;

  unsigned short* Wip   = W;
  unsigned short* Wout  = W + 786432;
  unsigned short* Wfc1  = W + 1048576;
  unsigned short* Wfc2  = W + 1572864;
  unsigned short* Wq    = W + 2097152;
  unsigned short* Wkv   = W + 2359296;
  unsigned short* Wproj = W + 2883584;
  unsigned short* Whead = W + 3145728;

  auto cvt = [&](const float* s, unsigned short* d, int n) {
    cvt_f32_bf16<<<dim3((n / 4 + 255) / 256), dim3(256), 0, stream>>>(s, d, n / 4);
  };
  cvt(in_proj_w, Wip, 786432);
  cvt(out_w, Wout, 262144);
  cvt(fc1_w, Wfc1, 524288);
  cvt(fc2_w, Wfc2, 524288);
  cvt(q_w, Wq, 262144);
  cvt(kv_w, Wkv, 524288);
  cvt(proj_w, Wproj, 262144);
  cvt(head_w, Whead, 4194304);

  // ---- encoders (left+right batched, M=12288) ----
  embed_k<<<dim3(6144), dim3(256), 0, stream>>>(targets, pad_p, char_emb, ltok, rtok, X);
  ln_rows<<<dim3(3072), dim3(256), 0, stream>>>(X, ln1_g, ln1_b, A1, 12288);
  gemm_bt<0,0,1,0><<<dim3(12, 96), dim3(256), 0, stream>>>(A1, Wip, in_proj_b, nullptr, QKV, 12288, 1536, 512);
  winattn<<<dim3(768), dim3(256), 0, stream>>>(QKV, B1);
  gemm_bt<1,0,0,0><<<dim3(4, 96), dim3(256), 0, stream>>>(B1, Wout, out_b, X, X, 12288, 512, 512);
  ln_rows<<<dim3(3072), dim3(256), 0, stream>>>(X, ln2_g, ln2_b, A1, 12288);
  gemm_bt<0,1,1,0><<<dim3(8, 96), dim3(256), 0, stream>>>(A1, Wfc1, fc1_b, nullptr, B1, 12288, 1024, 512);
  gemm_bt<1,0,0,0><<<dim3(4, 96), dim3(256), 0, stream>>>(B1, Wfc2, fc2_b, X, X, 12288, 512, 1024);
  mean3<<<dim3(2048), dim3(256), 0, stream>>>(X, ENC);

  // ---- cross attention (kv shared by both sides; encoder buffers now dead) ----
  ln_rows<<<dim3(8192), dim3(256), 0, stream>>>(visual, lnkv_g, lnkv_b, VIS, 32768);
  gemm_bt<0,0,1,1><<<dim3(8, 256), dim3(256), 0, stream>>>(VIS, Wkv, kv_b, nullptr, KP, 32768, 1024, 512);
  ln_rows<<<dim3(1024), dim3(256), 0, stream>>>(ENC, lnq_g, lnq_b, LNQ, 4096);
  gemm_bt<0,0,0,0><<<dim3(4, 32), dim3(256), 0, stream>>>(LNQ, Wq, q_b, nullptr, Q, 4096, 512, 512);
  crossattn_mfma<<<dim3(1024), dim3(256), 0, stream>>>(Q, KP, VPT, OC);
  gemm_bt<1,0,1,0><<<dim3(4, 32), dim3(256), 0, stream>>>(OC, Wproj, proj_b, ENC, FEAT, 4096, 512, 512);

  // ---- head -> d_out (rows 0..2047 = sgm_left, 2048..4095 = sgm_right) ----
  gemm_bt<0,0,0,0><<<dim3(64, 32), dim3(256), 0, stream>>>(FEAT, Whead, head_b, nullptr, (float*)d_out, 4096, 8192, 512);
  tail_targets<<<dim3(8), dim3(256), 0, stream>>>(targets, (float*)d_out);
}